// Round 1
// baseline (3053.233 us; speedup 1.0000x reference)
//
#include <hip/hip_runtime.h>

#define N_NODES 100000
#define N_EDGES 1600000
#define D 64
#define BN_EPS 1e-5f

// 16 threads per edge; each thread handles 4 consecutive floats (float4).
// Gathers src row (coalesced 256B per edge across its 16 lanes), atomically
// accumulates into dst row. Lane 0 of each edge-group bumps the degree count
// (only on the first pass; degree is identical for both layers).
__global__ __launch_bounds__(256) void edge_scatter(
    const int* __restrict__ ei, const float* __restrict__ xin,
    float* __restrict__ s, float* __restrict__ cnt, int do_cnt) {
  long tid = (long)blockIdx.x * 256 + threadIdx.x;
  int e = (int)(tid >> 4);
  int part = (int)(tid & 15);
  if (e >= N_EDGES) return;
  int src = ei[e];
  int dst = ei[N_EDGES + e];
  float4 v = *(const float4*)(xin + (long)src * D + part * 4);
  float* sp = s + (long)dst * D + part * 4;
  atomicAdd(sp + 0, v.x);
  atomicAdd(sp + 1, v.y);
  atomicAdd(sp + 2, v.z);
  atomicAdd(sp + 3, v.w);
  if (do_cnt && part == 0) atomicAdd(cnt + dst, 1.0f);
}

// One thread per node. Fused: agg = s/max(cnt,1); h = agg@Wl^T + bl + x@Wr^T;
// ELU; BatchNorm(eval). Weights live in LDS and are read at wave-uniform
// addresses (broadcast, conflict-free). Row data lives in registers with
// static (fully unrolled) indexing.
__global__ __launch_bounds__(256) void node_update(
    const float* __restrict__ s, const float* __restrict__ cnt,
    const float* __restrict__ xin,
    const float* __restrict__ wl, const float* __restrict__ bl,
    const float* __restrict__ wr,
    const float* __restrict__ gamma, const float* __restrict__ beta,
    const float* __restrict__ mean, const float* __restrict__ var,
    float* __restrict__ out) {
  __shared__ float lwl[D * D];
  __shared__ float lwr[D * D];
  __shared__ float lsc[D];
  __shared__ float lsh[D];
  int tid = threadIdx.x;
  for (int i = tid; i < D * D; i += 256) {
    lwl[i] = wl[i];
    lwr[i] = wr[i];
  }
  if (tid < D) {
    float sc = gamma[tid] * rsqrtf(var[tid] + BN_EPS);
    lsc[tid] = sc;
    lsh[tid] = beta[tid] - mean[tid] * sc;
  }
  __syncthreads();

  int n = blockIdx.x * 256 + tid;
  if (n >= N_NODES) return;

  float inv = 1.0f / fmaxf(cnt[n], 1.0f);
  float xr[D], ar[D];
  const float4* xp = (const float4*)(xin + (long)n * D);
  const float4* sp = (const float4*)(s + (long)n * D);
#pragma unroll
  for (int i = 0; i < D / 4; ++i) {
    float4 xv = xp[i];
    float4 sv = sp[i];
    xr[4 * i + 0] = xv.x; xr[4 * i + 1] = xv.y;
    xr[4 * i + 2] = xv.z; xr[4 * i + 3] = xv.w;
    ar[4 * i + 0] = sv.x * inv; ar[4 * i + 1] = sv.y * inv;
    ar[4 * i + 2] = sv.z * inv; ar[4 * i + 3] = sv.w * inv;
  }

  float4* op = (float4*)(out + (long)n * D);
  for (int d0 = 0; d0 < D; d0 += 4) {
    float acc0 = bl[d0 + 0];
    float acc1 = bl[d0 + 1];
    float acc2 = bl[d0 + 2];
    float acc3 = bl[d0 + 3];
#pragma unroll
    for (int k = 0; k < D; ++k) {
      float a = ar[k], x = xr[k];
      acc0 += a * lwl[(d0 + 0) * D + k] + x * lwr[(d0 + 0) * D + k];
      acc1 += a * lwl[(d0 + 1) * D + k] + x * lwr[(d0 + 1) * D + k];
      acc2 += a * lwl[(d0 + 2) * D + k] + x * lwr[(d0 + 2) * D + k];
      acc3 += a * lwl[(d0 + 3) * D + k] + x * lwr[(d0 + 3) * D + k];
    }
    float4 o;
    float vv;
    vv = acc0; vv = vv > 0.f ? vv : expm1f(vv); o.x = vv * lsc[d0 + 0] + lsh[d0 + 0];
    vv = acc1; vv = vv > 0.f ? vv : expm1f(vv); o.y = vv * lsc[d0 + 1] + lsh[d0 + 1];
    vv = acc2; vv = vv > 0.f ? vv : expm1f(vv); o.z = vv * lsc[d0 + 2] + lsh[d0 + 2];
    vv = acc3; vv = vv > 0.f ? vv : expm1f(vv); o.w = vv * lsc[d0 + 3] + lsh[d0 + 3];
    op[d0 / 4] = o;
  }
}

extern "C" void kernel_launch(void* const* d_in, const int* in_sizes, int n_in,
                              void* d_out, int out_size, void* d_ws, size_t ws_size,
                              hipStream_t stream) {
  const float* x       = (const float*)d_in[0];
  const int*   ei      = (const int*)d_in[1];
  const float* w1_l    = (const float*)d_in[2];
  const float* b1_l    = (const float*)d_in[3];
  const float* w1_r    = (const float*)d_in[4];
  const float* w2_l    = (const float*)d_in[5];
  const float* b2_l    = (const float*)d_in[6];
  const float* w2_r    = (const float*)d_in[7];
  const float* bn1_g   = (const float*)d_in[8];
  const float* bn1_b   = (const float*)d_in[9];
  const float* bn1_m   = (const float*)d_in[10];
  const float* bn1_v   = (const float*)d_in[11];
  const float* bn2_g   = (const float*)d_in[12];
  const float* bn2_b   = (const float*)d_in[13];
  const float* bn2_m   = (const float*)d_in[14];
  const float* bn2_v   = (const float*)d_in[15];

  float* out = (float*)d_out;          // also reused as h1 storage
  float* s   = (float*)d_ws;           // [N_NODES * D]
  float* cnt = s + (size_t)N_NODES * D; // [N_NODES]

  const int edge_threads = N_EDGES * 16;
  const int edge_blocks = (edge_threads + 255) / 256;
  const int node_blocks = (N_NODES + 255) / 256;

  // ---- layer 1 ----
  hipMemsetAsync(d_ws, 0, ((size_t)N_NODES * D + N_NODES) * sizeof(float), stream);
  edge_scatter<<<edge_blocks, 256, 0, stream>>>(ei, x, s, cnt, 1);
  node_update<<<node_blocks, 256, 0, stream>>>(s, cnt, x, w1_l, b1_l, w1_r,
                                               bn1_g, bn1_b, bn1_m, bn1_v, out);
  // ---- layer 2 ----
  hipMemsetAsync(d_ws, 0, (size_t)N_NODES * D * sizeof(float), stream);
  edge_scatter<<<edge_blocks, 256, 0, stream>>>(ei, out, s, cnt, 0);
  node_update<<<node_blocks, 256, 0, stream>>>(s, cnt, out, w2_l, b2_l, w2_r,
                                               bn2_g, bn2_b, bn2_m, bn2_v, out);
}

// Round 2
// 747.704 us; speedup vs baseline: 4.0835x; 4.0835x over previous
//
#include <hip/hip_runtime.h>
#include <hip/hip_bf16.h>

#define N_NODES 100000
#define N_EDGES 1600000
#define D 64
#define BN_EPS 1e-5f
#define NB_SCAN 391  // ceil(N_NODES/256)

// ---------------- CSR build ----------------

__global__ __launch_bounds__(256) void k_hist(const int* __restrict__ ei,
                                              int* __restrict__ counts) {
  int e = blockIdx.x * 256 + threadIdx.x;
  if (e >= N_EDGES) return;
  atomicAdd(&counts[ei[N_EDGES + e]], 1);
}

__global__ __launch_bounds__(256) void k_bsum(const int* __restrict__ counts,
                                              int* __restrict__ bsums) {
  __shared__ int red[256];
  int tid = threadIdx.x;
  int i = blockIdx.x * 256 + tid;
  red[tid] = (i < N_NODES) ? counts[i] : 0;
  __syncthreads();
  for (int ofs = 128; ofs > 0; ofs >>= 1) {
    if (tid < ofs) red[tid] += red[tid + ofs];
    __syncthreads();
  }
  if (tid == 0) bsums[blockIdx.x] = red[0];
}

__global__ __launch_bounds__(512) void k_scan_bsums(int* __restrict__ bsums) {
  __shared__ int sd[512];
  int tid = threadIdx.x;
  int v = (tid < NB_SCAN) ? bsums[tid] : 0;
  sd[tid] = v;
  __syncthreads();
  for (int ofs = 1; ofs < 512; ofs <<= 1) {
    int t = (tid >= ofs) ? sd[tid - ofs] : 0;
    __syncthreads();
    sd[tid] += t;
    __syncthreads();
  }
  if (tid < NB_SCAN) bsums[tid] = sd[tid] - v;  // exclusive
}

// counts lives in the same buffer as cursor; each thread reads counts[i] then
// (after using only the LDS copy) overwrites cursor[i] -- single owner per i.
__global__ __launch_bounds__(256) void k_scan_final(
    const int* __restrict__ bsums, int* __restrict__ counts_cursor,
    int* __restrict__ offsets) {
  __shared__ int sd[256];
  int tid = threadIdx.x;
  int i = blockIdx.x * 256 + tid;
  int v = (i < N_NODES) ? counts_cursor[i] : 0;
  sd[tid] = v;
  __syncthreads();
  for (int ofs = 1; ofs < 256; ofs <<= 1) {
    int t = (tid >= ofs) ? sd[tid - ofs] : 0;
    __syncthreads();
    sd[tid] += t;
    __syncthreads();
  }
  int off = bsums[blockIdx.x] + sd[tid] - v;  // exclusive prefix
  if (i < N_NODES) {
    offsets[i] = off;
    counts_cursor[i] = off;  // cursor init for scatter
    if (i == N_NODES - 1) offsets[N_NODES] = off + v;
  }
}

__global__ __launch_bounds__(256) void k_scatter(const int* __restrict__ ei,
                                                 int* __restrict__ cursor,
                                                 int* __restrict__ ssrc) {
  int e = blockIdx.x * 256 + threadIdx.x;
  if (e >= N_EDGES) return;
  int src = ei[e];
  int dst = ei[N_EDGES + e];
  int pos = atomicAdd(&cursor[dst], 1);
  ssrc[pos] = src;
}

// ---------------- fused SAGE layer ----------------
// Per block: 64-node tile. Phase 1: gather-aggregate neighbor rows into LDS
// (wave per 16 nodes, lane = feature). Phase 2: register-tiled (4x4) GEMM
// over concat([agg | x]) @ concat([Wl; Wr])^T + bias, ELU, BN.

#define IS 130  // in_t row stride (floats); 4*IS mod 32 = 8 -> 4 distinct banks
#define WS 129  // w_t row stride;          4*WS mod 32 = 4 -> 8 distinct banks

template <bool IN_BF16>
__device__ inline float ld_feat(const void* p, long idx) {
  if constexpr (IN_BF16) {
    return __bfloat162float(((const __hip_bfloat16*)p)[idx]);
  } else {
    return ((const float*)p)[idx];
  }
}

static __device__ inline unsigned short f2bf_bits(float v) {
  __hip_bfloat16 h = __float2bfloat16(v);
  return *reinterpret_cast<unsigned short*>(&h);
}

template <bool IN_BF16, bool OUT_BF16>
__global__ __launch_bounds__(256) void sage_layer(
    const int* __restrict__ offsets, const int* __restrict__ ssrc,
    const void* __restrict__ xin,
    const float* __restrict__ wl, const float* __restrict__ bl,
    const float* __restrict__ wr,
    const float* __restrict__ gamma, const float* __restrict__ beta,
    const float* __restrict__ mean, const float* __restrict__ var,
    void* __restrict__ out) {
  __shared__ float in_t[64 * IS];
  __shared__ float w_t[64 * WS];
  __shared__ float lsc[D], lsh[D], lbl[D];

  int tid = threadIdx.x;
  int base = blockIdx.x * 64;

  // stage weights: w_t[d][k<64]=Wl[d][k], w_t[d][64+k]=Wr[d][k]
  for (int i = tid; i < D * D; i += 256) {
    int d = i >> 6, k = i & 63;
    w_t[d * WS + k] = wl[i];
    w_t[d * WS + 64 + k] = wr[i];
  }
  if (tid < D) {
    float sc = gamma[tid] * rsqrtf(var[tid] + BN_EPS);
    lsc[tid] = sc;
    lsh[tid] = beta[tid] - mean[tid] * sc;
    lbl[tid] = bl[tid];
  }

  // phase 1: aggregation. wave handles 16 nodes, lane = feature.
  int wave = tid >> 6, lane = tid & 63;
  for (int t = 0; t < 16; ++t) {
    int r = wave * 16 + t;
    int n = base + r;
    if (n < N_NODES) {
      int off = offsets[n];
      int deg = offsets[n + 1] - off;
      float acc = 0.f;
      int j = 0;
      while (j + 16 <= deg) {
        int idx = ssrc[off + j + (lane & 15)];
#pragma unroll
        for (int u = 0; u < 16; ++u) {
          int s = __shfl(idx, u, 64);
          acc += ld_feat<IN_BF16>(xin, (long)s * D + lane);
        }
        j += 16;
      }
      int rem = deg - j;
      if (rem > 0) {
        int idx = ((lane & 15) < rem) ? ssrc[off + j + (lane & 15)] : 0;
        for (int u = 0; u < rem; ++u) {
          int s = __shfl(idx, u, 64);
          acc += ld_feat<IN_BF16>(xin, (long)s * D + lane);
        }
      }
      float invd = 1.0f / fmaxf((float)deg, 1.0f);
      in_t[r * IS + lane] = acc * invd;
      in_t[r * IS + 64 + lane] = ld_feat<IN_BF16>(xin, (long)n * D + lane);
    } else {
      in_t[r * IS + lane] = 0.f;
      in_t[r * IS + 64 + lane] = 0.f;
    }
  }
  __syncthreads();

  // phase 2: GEMM. thread -> (node group, output group); 4 nodes x 4 outs.
  int ng = tid >> 4, og = tid & 15;
  int n0 = ng * 4, d0 = og * 4;
  float acc[4][4] = {{0.f}};
#pragma unroll 4
  for (int k = 0; k < 128; ++k) {
    float a0 = in_t[(n0 + 0) * IS + k];
    float a1 = in_t[(n0 + 1) * IS + k];
    float a2 = in_t[(n0 + 2) * IS + k];
    float a3 = in_t[(n0 + 3) * IS + k];
    float w0 = w_t[(d0 + 0) * WS + k];
    float w1 = w_t[(d0 + 1) * WS + k];
    float w2 = w_t[(d0 + 2) * WS + k];
    float w3 = w_t[(d0 + 3) * WS + k];
    acc[0][0] += a0 * w0; acc[0][1] += a0 * w1; acc[0][2] += a0 * w2; acc[0][3] += a0 * w3;
    acc[1][0] += a1 * w0; acc[1][1] += a1 * w1; acc[1][2] += a1 * w2; acc[1][3] += a1 * w3;
    acc[2][0] += a2 * w0; acc[2][1] += a2 * w1; acc[2][2] += a2 * w2; acc[2][3] += a2 * w3;
    acc[3][0] += a3 * w0; acc[3][1] += a3 * w1; acc[3][2] += a3 * w2; acc[3][3] += a3 * w3;
  }

  // epilogue: +bias, ELU, BN, store
#pragma unroll
  for (int i = 0; i < 4; ++i) {
    int n = base + n0 + i;
    if (n >= N_NODES) continue;
    float o[4];
#pragma unroll
    for (int j = 0; j < 4; ++j) {
      float v = acc[i][j] + lbl[d0 + j];
      v = v > 0.f ? v : expm1f(v);
      o[j] = v * lsc[d0 + j] + lsh[d0 + j];
    }
    if constexpr (OUT_BF16) {
      ushort4 pk;
      pk.x = f2bf_bits(o[0]); pk.y = f2bf_bits(o[1]);
      pk.z = f2bf_bits(o[2]); pk.w = f2bf_bits(o[3]);
      *(ushort4*)((__hip_bfloat16*)out + (long)n * D + d0) = pk;
    } else {
      float4 f;
      f.x = o[0]; f.y = o[1]; f.z = o[2]; f.w = o[3];
      *(float4*)((float*)out + (long)n * D + d0) = f;
    }
  }
}

// ---------------- launch ----------------

extern "C" void kernel_launch(void* const* d_in, const int* in_sizes, int n_in,
                              void* d_out, int out_size, void* d_ws, size_t ws_size,
                              hipStream_t stream) {
  const float* x     = (const float*)d_in[0];
  const int*   ei    = (const int*)d_in[1];
  const float* w1_l  = (const float*)d_in[2];
  const float* b1_l  = (const float*)d_in[3];
  const float* w1_r  = (const float*)d_in[4];
  const float* w2_l  = (const float*)d_in[5];
  const float* b2_l  = (const float*)d_in[6];
  const float* w2_r  = (const float*)d_in[7];
  const float* bn1_g = (const float*)d_in[8];
  const float* bn1_b = (const float*)d_in[9];
  const float* bn1_m = (const float*)d_in[10];
  const float* bn1_v = (const float*)d_in[11];
  const float* bn2_g = (const float*)d_in[12];
  const float* bn2_b = (const float*)d_in[13];
  const float* bn2_m = (const float*)d_in[14];
  const float* bn2_v = (const float*)d_in[15];

  // ws layout (ints then bf16 h1): total ~20.0 MB
  int* offsets = (int*)d_ws;                 // [N+1]
  int* cursor  = offsets + 100016;           // [N] (counts, then cursor)
  int* bsums   = cursor + 100016;            // [512]
  int* ssrc    = bsums + 512;                // [E]
  __hip_bfloat16* h1 = (__hip_bfloat16*)(ssrc + N_EDGES);  // [N*D]

  const int eb = (N_EDGES + 255) / 256;
  const int tiles = (N_NODES + 63) / 64;

  // CSR build (once; shared by both layers)
  hipMemsetAsync(cursor, 0, N_NODES * sizeof(int), stream);
  k_hist<<<eb, 256, 0, stream>>>(ei, cursor);
  k_bsum<<<NB_SCAN, 256, 0, stream>>>(cursor, bsums);
  k_scan_bsums<<<1, 512, 0, stream>>>(bsums);
  k_scan_final<<<NB_SCAN, 256, 0, stream>>>(bsums, cursor, offsets);
  k_scatter<<<eb, 256, 0, stream>>>(ei, cursor, ssrc);

  // layer 1: f32 in -> bf16 h1 (ws)
  sage_layer<false, true><<<tiles, 256, 0, stream>>>(
      offsets, ssrc, x, w1_l, b1_l, w1_r, bn1_g, bn1_b, bn1_m, bn1_v, h1);
  // layer 2: bf16 h1 -> f32 out
  sage_layer<true, false><<<tiles, 256, 0, stream>>>(
      offsets, ssrc, h1, w2_l, b2_l, w2_r, bn2_g, bn2_b, bn2_m, bn2_v, d_out);
}

// Round 3
// 491.063 us; speedup vs baseline: 6.2176x; 1.5226x over previous
//
#include <hip/hip_runtime.h>
#include <hip/hip_bf16.h>

#define N_NODES 100000
#define N_EDGES 1600000
#define D 64
#define BN_EPS 1e-5f
#define NB_SCAN 391  // ceil(N_NODES/256)
#define ROWSTR 132   // in_t row stride (floats): 16B-aligned quads, even bank spread

// ---------------- CSR build ----------------

__global__ __launch_bounds__(256) void k_hist4(const int* __restrict__ ei,
                                               int* __restrict__ counts) {
  int e = (blockIdx.x * 256 + threadIdx.x) * 4;
  if (e >= N_EDGES) return;
  int4 d = *(const int4*)(ei + N_EDGES + e);
  atomicAdd(&counts[d.x], 1);
  atomicAdd(&counts[d.y], 1);
  atomicAdd(&counts[d.z], 1);
  atomicAdd(&counts[d.w], 1);
}

__global__ __launch_bounds__(256) void k_bsum(const int* __restrict__ counts,
                                              int* __restrict__ bsums) {
  __shared__ int red[256];
  int tid = threadIdx.x;
  int i = blockIdx.x * 256 + tid;
  red[tid] = (i < N_NODES) ? counts[i] : 0;
  __syncthreads();
  for (int ofs = 128; ofs > 0; ofs >>= 1) {
    if (tid < ofs) red[tid] += red[tid + ofs];
    __syncthreads();
  }
  if (tid == 0) bsums[blockIdx.x] = red[0];
}

__global__ __launch_bounds__(512) void k_scan_bsums(int* __restrict__ bsums) {
  __shared__ int sd[512];
  int tid = threadIdx.x;
  int v = (tid < NB_SCAN) ? bsums[tid] : 0;
  sd[tid] = v;
  __syncthreads();
  for (int ofs = 1; ofs < 512; ofs <<= 1) {
    int t = (tid >= ofs) ? sd[tid - ofs] : 0;
    __syncthreads();
    sd[tid] += t;
    __syncthreads();
  }
  if (tid < NB_SCAN) bsums[tid] = sd[tid] - v;  // exclusive
}

__global__ __launch_bounds__(256) void k_scan_final(
    const int* __restrict__ bsums, int* __restrict__ counts_cursor,
    int* __restrict__ offsets) {
  __shared__ int sd[256];
  int tid = threadIdx.x;
  int i = blockIdx.x * 256 + tid;
  int v = (i < N_NODES) ? counts_cursor[i] : 0;
  sd[tid] = v;
  __syncthreads();
  for (int ofs = 1; ofs < 256; ofs <<= 1) {
    int t = (tid >= ofs) ? sd[tid - ofs] : 0;
    __syncthreads();
    sd[tid] += t;
    __syncthreads();
  }
  int off = bsums[blockIdx.x] + sd[tid] - v;  // exclusive prefix
  if (i < N_NODES) {
    offsets[i] = off;
    counts_cursor[i] = off;  // cursor init for scatter
    if (i == N_NODES - 1) offsets[N_NODES] = off + v;
  }
}

__global__ __launch_bounds__(256) void k_scatter4(const int* __restrict__ ei,
                                                  int* __restrict__ cursor,
                                                  int* __restrict__ ssrc) {
  int e = (blockIdx.x * 256 + threadIdx.x) * 4;
  if (e >= N_EDGES) return;
  int4 s = *(const int4*)(ei + e);
  int4 d = *(const int4*)(ei + N_EDGES + e);
  int p;
  p = atomicAdd(&cursor[d.x], 1); ssrc[p] = s.x;
  p = atomicAdd(&cursor[d.y], 1); ssrc[p] = s.y;
  p = atomicAdd(&cursor[d.z], 1); ssrc[p] = s.z;
  p = atomicAdd(&cursor[d.w], 1); ssrc[p] = s.w;
}

// ---------------- fused SAGE layer ----------------

template <bool BF>
__device__ inline float4 ld_quad(const void* p, long row, int q) {
  if constexpr (BF) {
    ushort4 u = *(const ushort4*)((const unsigned short*)p + row * D + q * 4);
    float4 f;
    unsigned int b;
    b = (unsigned int)u.x << 16; f.x = *(float*)&b;
    b = (unsigned int)u.y << 16; f.y = *(float*)&b;
    b = (unsigned int)u.z << 16; f.z = *(float*)&b;
    b = (unsigned int)u.w << 16; f.w = *(float*)&b;
    return f;
  } else {
    return *(const float4*)((const float*)p + row * D + q * 4);
  }
}

static __device__ inline unsigned short f2bf_bits(float v) {
  __hip_bfloat16 h = __float2bfloat16(v);
  return *reinterpret_cast<unsigned short*>(&h);
}

template <bool IN_BF16, bool OUT_BF16>
__global__ __launch_bounds__(256) void sage_fused(
    const int* __restrict__ offsets, const int* __restrict__ ssrc,
    const void* __restrict__ xin,
    const float* __restrict__ wl, const float* __restrict__ bl,
    const float* __restrict__ wr,
    const float* __restrict__ gamma, const float* __restrict__ beta,
    const float* __restrict__ mean, const float* __restrict__ var,
    void* __restrict__ out) {
  __shared__ float in_t[64 * ROWSTR];
  const int tid = threadIdx.x;
  const int base = blockIdx.x * 64;
  const int grp = tid >> 4;  // 16-lane group id, 0..15
  const int q = tid & 15;    // feature quad

  // phase 1: gather-aggregate. group = node; lane = 4 features. 4 passes.
  for (int p = 0; p < 4; ++p) {
    int r = p * 16 + grp;
    int n = base + r;
    float4 acc = make_float4(0.f, 0.f, 0.f, 0.f);
    float4 xv = make_float4(0.f, 0.f, 0.f, 0.f);
    if (n < N_NODES) {
      int off = offsets[n];
      int deg = offsets[n + 1] - off;
      int u = 0;
      for (; u + 4 <= deg; u += 4) {
        int s0 = ssrc[off + u + 0];
        int s1 = ssrc[off + u + 1];
        int s2 = ssrc[off + u + 2];
        int s3 = ssrc[off + u + 3];
        float4 v0 = ld_quad<IN_BF16>(xin, s0, q);
        float4 v1 = ld_quad<IN_BF16>(xin, s1, q);
        float4 v2 = ld_quad<IN_BF16>(xin, s2, q);
        float4 v3 = ld_quad<IN_BF16>(xin, s3, q);
        acc.x += (v0.x + v1.x) + (v2.x + v3.x);
        acc.y += (v0.y + v1.y) + (v2.y + v3.y);
        acc.z += (v0.z + v1.z) + (v2.z + v3.z);
        acc.w += (v0.w + v1.w) + (v2.w + v3.w);
      }
      for (; u < deg; ++u) {
        float4 v = ld_quad<IN_BF16>(xin, ssrc[off + u], q);
        acc.x += v.x; acc.y += v.y; acc.z += v.z; acc.w += v.w;
      }
      float invd = 1.0f / fmaxf((float)deg, 1.0f);
      acc.x *= invd; acc.y *= invd; acc.z *= invd; acc.w *= invd;
      xv = ld_quad<IN_BF16>(xin, n, q);
    }
    *(float4*)&in_t[r * ROWSTR + q * 4] = acc;
    *(float4*)&in_t[r * ROWSTR + 64 + q * 4] = xv;
  }
  __syncthreads();

  // phase 2: thread = (node = tid&63, dim-block g = wave). Weights wave-uniform
  // -> scalar (SGPR) loads. 16 outputs/thread in 4 quads.
  const int n = tid & 63;
  const int g = __builtin_amdgcn_readfirstlane(tid >> 6);  // 0..3
  const long gn = base + n;
  const float* inrow = &in_t[n * ROWSTR];

  for (int dt = 0; dt < 4; ++dt) {
    const int d0 = g * 16 + dt * 4;
    float a0 = bl[d0 + 0], a1 = bl[d0 + 1], a2 = bl[d0 + 2], a3 = bl[d0 + 3];
    const float* w0l = wl + (long)(d0 + 0) * 64;
    const float* w1l = wl + (long)(d0 + 1) * 64;
    const float* w2l = wl + (long)(d0 + 2) * 64;
    const float* w3l = wl + (long)(d0 + 3) * 64;
    const float* w0r = wr + (long)(d0 + 0) * 64;
    const float* w1r = wr + (long)(d0 + 1) * 64;
    const float* w2r = wr + (long)(d0 + 2) * 64;
    const float* w3r = wr + (long)(d0 + 3) * 64;
#pragma unroll
    for (int k = 0; k < 64; k += 4) {
      float4 iv = *(const float4*)(inrow + k);       // agg half
      float4 jv = *(const float4*)(inrow + 64 + k);  // x half
      a0 += iv.x * w0l[k] + iv.y * w0l[k + 1] + iv.z * w0l[k + 2] + iv.w * w0l[k + 3]
          + jv.x * w0r[k] + jv.y * w0r[k + 1] + jv.z * w0r[k + 2] + jv.w * w0r[k + 3];
      a1 += iv.x * w1l[k] + iv.y * w1l[k + 1] + iv.z * w1l[k + 2] + iv.w * w1l[k + 3]
          + jv.x * w1r[k] + jv.y * w1r[k + 1] + jv.z * w1r[k + 2] + jv.w * w1r[k + 3];
      a2 += iv.x * w2l[k] + iv.y * w2l[k + 1] + iv.z * w2l[k + 2] + iv.w * w2l[k + 3]
          + jv.x * w2r[k] + jv.y * w2r[k + 1] + jv.z * w2r[k + 2] + jv.w * w2r[k + 3];
      a3 += iv.x * w3l[k] + iv.y * w3l[k + 1] + iv.z * w3l[k + 2] + iv.w * w3l[k + 3]
          + jv.x * w3r[k] + jv.y * w3r[k + 1] + jv.z * w3r[k + 2] + jv.w * w3r[k + 3];
    }
    if (gn < N_NODES) {
      float sc0 = gamma[d0 + 0] * rsqrtf(var[d0 + 0] + BN_EPS);
      float sc1 = gamma[d0 + 1] * rsqrtf(var[d0 + 1] + BN_EPS);
      float sc2 = gamma[d0 + 2] * rsqrtf(var[d0 + 2] + BN_EPS);
      float sc3 = gamma[d0 + 3] * rsqrtf(var[d0 + 3] + BN_EPS);
      float sh0 = beta[d0 + 0] - mean[d0 + 0] * sc0;
      float sh1 = beta[d0 + 1] - mean[d0 + 1] * sc1;
      float sh2 = beta[d0 + 2] - mean[d0 + 2] * sc2;
      float sh3 = beta[d0 + 3] - mean[d0 + 3] * sc3;
      float o0 = a0 > 0.f ? a0 : expm1f(a0);
      float o1 = a1 > 0.f ? a1 : expm1f(a1);
      float o2 = a2 > 0.f ? a2 : expm1f(a2);
      float o3 = a3 > 0.f ? a3 : expm1f(a3);
      o0 = o0 * sc0 + sh0; o1 = o1 * sc1 + sh1;
      o2 = o2 * sc2 + sh2; o3 = o3 * sc3 + sh3;
      if constexpr (OUT_BF16) {
        ushort4 pk;
        pk.x = f2bf_bits(o0); pk.y = f2bf_bits(o1);
        pk.z = f2bf_bits(o2); pk.w = f2bf_bits(o3);
        *(ushort4*)((unsigned short*)out + gn * D + d0) = pk;
      } else {
        float4 f;
        f.x = o0; f.y = o1; f.z = o2; f.w = o3;
        *(float4*)((float*)out + gn * D + d0) = f;
      }
    }
  }
}

// ---------------- launch ----------------

extern "C" void kernel_launch(void* const* d_in, const int* in_sizes, int n_in,
                              void* d_out, int out_size, void* d_ws, size_t ws_size,
                              hipStream_t stream) {
  const float* x     = (const float*)d_in[0];
  const int*   ei    = (const int*)d_in[1];
  const float* w1_l  = (const float*)d_in[2];
  const float* b1_l  = (const float*)d_in[3];
  const float* w1_r  = (const float*)d_in[4];
  const float* w2_l  = (const float*)d_in[5];
  const float* b2_l  = (const float*)d_in[6];
  const float* w2_r  = (const float*)d_in[7];
  const float* bn1_g = (const float*)d_in[8];
  const float* bn1_b = (const float*)d_in[9];
  const float* bn1_m = (const float*)d_in[10];
  const float* bn1_v = (const float*)d_in[11];
  const float* bn2_g = (const float*)d_in[12];
  const float* bn2_b = (const float*)d_in[13];
  const float* bn2_m = (const float*)d_in[14];
  const float* bn2_v = (const float*)d_in[15];

  // ws layout: ~20 MB
  int* offsets = (int*)d_ws;                 // [N+1] (+pad)
  int* cursor  = offsets + 100016;           // [N] counts, then cursor
  int* bsums   = cursor + 100016;            // [512]
  int* ssrc    = bsums + 512;                // [E]
  unsigned short* h1 = (unsigned short*)(ssrc + N_EDGES);  // bf16 [N*D]

  const int eb4 = (N_EDGES / 4 + 255) / 256;
  const int tiles = (N_NODES + 63) / 64;

  hipMemsetAsync(cursor, 0, N_NODES * sizeof(int), stream);
  k_hist4<<<eb4, 256, 0, stream>>>(ei, cursor);
  k_bsum<<<NB_SCAN, 256, 0, stream>>>(cursor, bsums);
  k_scan_bsums<<<1, 512, 0, stream>>>(bsums);
  k_scan_final<<<NB_SCAN, 256, 0, stream>>>(bsums, cursor, offsets);
  k_scatter4<<<eb4, 256, 0, stream>>>(ei, cursor, ssrc);

  sage_fused<false, true><<<tiles, 256, 0, stream>>>(
      offsets, ssrc, x, w1_l, b1_l, w1_r, bn1_g, bn1_b, bn1_m, bn1_v, h1);
  sage_fused<true, false><<<tiles, 256, 0, stream>>>(
      offsets, ssrc, h1, w2_l, b2_l, w2_r, bn2_g, bn2_b, bn2_m, bn2_v, d_out);
}